// Round 1
// baseline (215.199 us; speedup 1.0000x reference)
//
#include <hip/hip_runtime.h>

#define PI_F 3.14159265358979323846f

typedef short bf16x8 __attribute__((ext_vector_type(8)));
typedef float f32x4 __attribute__((ext_vector_type(4)));

#define MFMA16(acc, a, b) \
  acc = __builtin_amdgcn_mfma_f32_16x16x32_bf16(a, b, acc, 0, 0, 0)

// ---------------- workspace layout (float offsets) ----------------
#define WS_SPEC   0u          // 32*128*1024  [b][t][k]
#define WS_H0     4194304u    // 32*32*128    [b][o][t]
#define WS_ACC    4325376u    // 32*128*32    [b][t][o]
#define WS_V      4456448u    // 32*32*128    [b][c][t]; ALSO: k_prep stashes the
                              // chain-weight bf16 packs in the first 16384 floats
                              // (region only becomes v after k_sparse_dense,
                              // which runs after k_chain has consumed the packs)
#define WS_WTIN   4587520u    // 1024*32      [k][o]
#define WS_WST    4620288u    // 32*256       [m][o2]
#define WS_WDT    4628480u    // 256*32       [o2][c]
#define WS_FRAMES 4636672u    // 32*32*2048   [c][f][j]; after k_res_assemble this
                              // region is DEAD -> reused for Bh/Bl bf16 packs
#define WS_RES    6733824u    // 32*32768     [c][s]
// total 7782400 floats = ~29.7 MB

// ---- 2048-pt complex DIT FFT, input already in bit-reversed order, 256 thr ----
__device__ __forceinline__ void fft2048_stages(float2* buf, int tid) {
  for (int stage = 0; stage < 11; ++stage) {
    int half = 1 << stage;
    float base = -PI_F / (float)half;   // -2*pi/len
    for (int t = tid; t < 1024; t += 256) {
      int j  = t & (half - 1);
      int i0 = ((t >> stage) << (stage + 1)) + j;
      int i1 = i0 + half;
      float s, c;
      __sincosf(base * (float)j, &s, &c);   // e^{-i*2pi/len*j} = c + i*s
      float2 u = buf[i0];
      float2 w = buf[i1];
      float tr = c * w.x - s * w.y;
      float ti = c * w.y + s * w.x;
      buf[i0] = make_float2(u.x + tr, u.y + ti);
      buf[i1] = make_float2(u.x - tr, u.y - ti);
    }
    __syncthreads();
  }
}

// ---------------- fused FFT kernel: STFT pairs + resonance-frame pairs ----------------
__global__ __launch_bounds__(256) void k_fft(const float* __restrict__ audio,
                                             const float* __restrict__ resin,
                                             float* __restrict__ spec,
                                             float* __restrict__ frames) {
  __shared__ float2 buf[2048];
  int blk = blockIdx.x;
  if (blk < 2048) {
    int b  = blk >> 6;
    int f0 = (blk & 63) * 2;      // frames f0, f0+1
    for (int j = threadIdx.x; j < 2048; j += 256) {
      float h = 0.5f - 0.5f * __cosf(0.0030679615757712823f * (float)j); // 2pi/2048
      int i1 = f0 * 256 + j;
      int i2 = i1 + 256;
      float a1 = (i1 < 32768) ? audio[b * 32768 + i1] : 0.f;
      float a2 = (i2 < 32768) ? audio[b * 32768 + i2] : 0.f;
      buf[__brev((unsigned)j) >> 21] = make_float2(a1 * h, a2 * h);
    }
    __syncthreads();
    fft2048_stages(buf, threadIdx.x);
    const float scale = 0.5f * 0.022097086912079608f;  // 0.5 / sqrt(2048)
    for (int k = threadIdx.x; k < 1024; k += 256) {
      float2 zk = buf[k];
      float2 zn = buf[(2048 - k) & 2047];
      float f1r = zk.x + zn.x, f1i = zk.y - zn.y;
      float f2r = zk.y + zn.y, f2i = zk.x - zn.x;
      spec[(b * 128 + f0) * 1024 + k]     = sqrtf(f1r * f1r + f1i * f1i) * scale;
      spec[(b * 128 + f0 + 1) * 1024 + k] = sqrtf(f2r * f2r + f2i * f2i) * scale;
    }
  } else {
    int r = blk - 2048;           // 0..511
    int c = r >> 4;
    int g = r & 15;               // frames 2g (exp 2g+1), 2g+1 (exp 2g+2)
    float e1 = (float)(2 * g + 1);
    for (int k = threadIdx.x; k < 2048; k += 256) {
      int kk = (k <= 1024) ? k : 2048 - k;   // Hermitian (real) extension
      float cv = resin[c * 1025 + kk];
      cv = fminf(fmaxf(cv, 0.f), 0.9999f);
      float m1 = __powf(cv, e1);
      float m2 = m1 * cv;
      buf[__brev((unsigned)k) >> 21] = make_float2(m1, m2);
    }
    __syncthreads();
    fft2048_stages(buf, threadIdx.x);
    for (int j = threadIdx.x; j < 2048; j += 256) {
      float h  = 0.5f - 0.5f * __cosf(0.0030679615757712823f * (float)j);
      float sc = h * (1.f / 2048.f);
      float2 z = buf[j];
      frames[(c * 32 + 2 * g) * 2048 + j]     = z.x * sc;
      frames[(c * 32 + 2 * g + 1) * 2048 + j] = z.y * sc;
    }
  }
}

// ---------------- weight transposes + chain-weight bf16 hi/lo packs ----------------
// Chain pack layout (B-fragment-native): row = (s*2 + which)*32 + o, 32 bf16/row;
// lane loads b128 at row*32 + quad*8 -> B[n=o][k=quad*8+j] for mfma.
__global__ __launch_bounds__(256) void k_prep(const float* __restrict__ Win,
                                              const float* __restrict__ Ws,
                                              const float* __restrict__ Wd,
                                              const float* __restrict__ bwIn,
                                              float* __restrict__ WT,
                                              float* __restrict__ WsT,
                                              float* __restrict__ WdT,
                                              short* __restrict__ Whg,
                                              short* __restrict__ Wlg) {
  int i = blockIdx.x * 256 + threadIdx.x;
  if (i < 32768) { int o = i >> 10, k = i & 1023; WT[k * 32 + o] = Win[i]; }
  if (i < 8192)  { int o2 = i >> 5, m = i & 31;   WsT[m * 256 + o2] = Ws[i]; }
  if (i < 8192)  { int c = i >> 8, o2 = i & 255;  WdT[o2 * 32 + c] = Wd[i]; }
  if (i < 16384) {
    // i = ((s*32+o)*32+m)*2 + w
    int w = i & 1, m = (i >> 1) & 31, o = (i >> 6) & 31, s = i >> 11;
    float val = bwIn[i];
    unsigned bits = __float_as_uint(val);
    float rem = val - __uint_as_float(bits & 0xffff0000u);
    int row = (s * 2 + w) * 32 + o;
    Whg[row * 32 + m] = (short)(bits >> 16);
    Wlg[row * 32 + m] = (short)(__float_as_uint(rem) >> 16);
  }
}

// ---------------- proj_in: h0[b,o,t] = sum_k WT[k][o]*spec[b,t,k] + bias ----------------
__global__ __launch_bounds__(256) void k_proj_in(const float* __restrict__ spec,
                                                 const float* __restrict__ WT,
                                                 const float* __restrict__ bias,
                                                 float* __restrict__ h0) {
  __shared__ float specL[8][1024];
  __shared__ float red[32][8][8];   // [o][tt][p]
  int b  = blockIdx.x >> 4;
  int t0 = (blockIdx.x & 15) * 8;
  for (int i = threadIdx.x; i < 8192; i += 256) {
    int tt = i >> 10, k = i & 1023;
    specL[tt][k] = spec[(b * 128 + t0 + tt) * 1024 + k];
  }
  __syncthreads();
  int o = threadIdx.x & 31, p = threadIdx.x >> 5;
  float part[8] = {0.f,0.f,0.f,0.f,0.f,0.f,0.f,0.f};
  for (int i = 0; i < 128; ++i) {
    int k = p * 128 + ((i + p * 4) & 127);   // stagger: conflict-free banks across p
    float w = WT[k * 32 + o];
#pragma unroll
    for (int tt = 0; tt < 8; ++tt) part[tt] += w * specL[tt][k];
  }
#pragma unroll
  for (int tt = 0; tt < 8; ++tt) red[o][tt][p] = part[tt];
  __syncthreads();
  int oo = threadIdx.x >> 3, tt2 = threadIdx.x & 7;
  float s = bias[oo];
#pragma unroll
  for (int p2 = 0; p2 < 8; ++p2) s += red[oo][tt2][p2];
  h0[b * 4096 + oo * 128 + t0 + tt2] = s;
}

// ---------------- 8-block anticausal chain as per-step MFMA GEMM pairs ----------------
// One block per batch (serial dependency: per-step global max). Per step:
// Y[128t x 32o] = H^T W0^T + Hshift^T W1^T + bias -> 16 waves x one 16x16 tile,
// 6 MFMA each (bf16 hi/lo split: AhBh + AhBl + AlBh per W). H stored in LDS as
// split-bf16 [t][ch] rows (b128 A-frag reads; rows 128..191 zeroed so the
// anticausal shift t+d reads zeros). Fragment maps identical to k_conv
// (validated): A[m=lane&15][k=quad*8+j], B[n=lane&15][k=quad*8+j],
// D row=quad*4+reg (t), col=lane&15 (o). Max-reduce: wave shuffle -> red[16] ->
// every thread folds 16 values (no serial section). 2 barriers/step.
__global__ __launch_bounds__(1024) void k_chain(const float* __restrict__ h0,
                                                const short* __restrict__ Whg,
                                                const short* __restrict__ Wlg,
                                                const float* __restrict__ bb,
                                                float* __restrict__ accout) {
  __shared__ __align__(16) short Hh[192 * 40];   // rows stride 40 bf16 (80 B)
  __shared__ __align__(16) short Hl[192 * 40];
  __shared__ float Hf[128 * 33];                 // fp32 H for exact residual
  __shared__ float bL[256];
  __shared__ float red[16];
  int b = blockIdx.x, tid = threadIdx.x;

  for (int i = tid; i < 4096; i += 1024) {
    int t = i & 127;                 // h0 layout [o][t]
    int o = i >> 7;
    float val = h0[b * 4096 + i];
    Hf[t * 33 + o] = val;
    unsigned bits = __float_as_uint(val);
    float rem = val - __uint_as_float(bits & 0xffff0000u);
    Hh[t * 40 + o] = (short)(bits >> 16);
    Hl[t * 40 + o] = (short)(__float_as_uint(rem) >> 16);
  }
  for (int i = tid; i < 64 * 40; i += 1024) {    // zero pad rows 128..191
    Hh[128 * 40 + i] = 0;
    Hl[128 * 40 + i] = 0;
  }
  if (tid < 256) bL[tid] = bb[tid];
  __syncthreads();

  int wave = tid >> 6, lane = tid & 63;
  int quad = lane >> 4, l15 = lane & 15;
  int t0 = (wave & 7) * 16, o0 = (wave >> 3) * 16;
  int tD = t0 + quad * 4;          // D rows tD..tD+3
  int oD = o0 + l15;               // D col

  const bf16x8* Hh8 = (const bf16x8*)Hh;   // unit = row*5 + quad (40 bf16 = 5 units)
  const bf16x8* Hl8 = (const bf16x8*)Hl;
  const bf16x8* Wh8 = (const bf16x8*)Whg;  // unit = row*4 + quad (32 bf16 = 4 units)
  const bf16x8* Wl8 = (const bf16x8*)Wlg;

  float accsum[4] = {0.f, 0.f, 0.f, 0.f};
  const int DIL[8] = {1, 2, 4, 8, 16, 32, 64, 1};

#pragma unroll
  for (int s = 0; s < 8; ++s) {
    int arow = t0 + l15;
    int frow = arow + DIL[s];        // <= 191, pad rows give zeros
    bf16x8 Ah = Hh8[arow * 5 + quad];
    bf16x8 Al = Hl8[arow * 5 + quad];
    bf16x8 Fh = Hh8[frow * 5 + quad];
    bf16x8 Fl = Hl8[frow * 5 + quad];
    int w0row = ((s * 2 + 0) * 32 + oD) * 4 + quad;
    int w1row = ((s * 2 + 1) * 32 + oD) * 4 + quad;
    bf16x8 B0h = Wh8[w0row], B0l = Wl8[w0row];
    bf16x8 B1h = Wh8[w1row], B1l = Wl8[w1row];
    float bias = bL[s * 32 + oD];
    f32x4 acc = {bias, bias, bias, bias};
    MFMA16(acc, Ah, B0h); MFMA16(acc, Ah, B0l); MFMA16(acc, Al, B0h);
    MFMA16(acc, Fh, B1h); MFMA16(acc, Fh, B1l); MFMA16(acc, Fl, B1h);
    float hnew[4], lmax = 0.f;
#pragma unroll
    for (int r = 0; r < 4; ++r) {
      float sv = acc[r];
      sv = (sv > 0.f) ? sv : 0.2f * sv;       // leaky_relu 0.2
      sv += Hf[(tD + r) * 33 + oD];           // residual (exact fp32)
      hnew[r] = sv;
      lmax = fmaxf(lmax, fabsf(sv));
    }
#pragma unroll
    for (int off = 32; off > 0; off >>= 1)
      lmax = fmaxf(lmax, __shfl_down(lmax, off, 64));
    if (lane == 0) red[wave] = lmax;
    __syncthreads();                 // red visible; all H reads of this step done
    float mx = red[0];
#pragma unroll
    for (int i = 1; i < 16; ++i) mx = fmaxf(mx, red[i]);
    float nm = 1.f / (mx + 1e-8f);
#pragma unroll
    for (int r = 0; r < 4; ++r) {
      float hv = hnew[r] * nm;
      accsum[r] += hv;
      int t = tD + r;
      Hf[t * 33 + oD] = hv;
      unsigned bits = __float_as_uint(hv);
      float rem = hv - __uint_as_float(bits & 0xffff0000u);
      Hh[t * 40 + oD] = (short)(bits >> 16);
      Hl[t * 40 + oD] = (short)(__float_as_uint(rem) >> 16);
    }
    __syncthreads();                 // new H visible for next step
  }
#pragma unroll
  for (int r = 0; r < 4; ++r)
    accout[b * 4096 + (tD + r) * 32 + oD] = accsum[r];
}

// ---------------- sparse (relu proj 32->256, to d_out) + dense (256->32, to ws) ----------------
__global__ __launch_bounds__(256) void k_sparse_dense(const float* __restrict__ acc,
                                                      const float* __restrict__ WsT,
                                                      const float* __restrict__ bs,
                                                      const float* __restrict__ WdT,
                                                      const float* __restrict__ bd,
                                                      float* __restrict__ out_sparse,
                                                      float* __restrict__ v) {
  __shared__ float accL[32];
  __shared__ float sL[256];
  __shared__ float red[8][32];
  int b = blockIdx.x >> 7, t = blockIdx.x & 127;
  int tid = threadIdx.x;
  if (tid < 32) accL[tid] = acc[b * 4096 + t * 32 + tid];
  __syncthreads();
  float s = bs[tid];
  for (int m = 0; m < 32; ++m) s += WsT[m * 256 + tid] * accL[m];
  s = fmaxf(s, 0.f);
  out_sparse[b * 32768 + tid * 128 + t] = s;
  sL[tid] = s;
  __syncthreads();
  int c = tid & 31, p = tid >> 5;
  float part = 0.f;
  for (int j = 0; j < 32; ++j) {
    int o2 = p * 32 + j;
    part += WdT[o2 * 32 + c] * sL[o2];
  }
  red[p][c] = part;
  __syncthreads();
  if (tid < 32) {
    float vv = bd[tid];
    for (int p2 = 0; p2 < 8; ++p2) vv += red[p2][tid];
    v[b * 4096 + tid * 128 + t] = vv;
  }
}

// ---------------- overlap-add (hop 1024): at most 2 frames per sample ----------------
__global__ __launch_bounds__(256) void k_res_assemble(const float* __restrict__ frames,
                                                      float* __restrict__ res) {
  int i = blockIdx.x * 256 + threadIdx.x;   // 0 .. 32*32768
  int c = i >> 15, s = i & 32767;
  int g = s >> 10, j0 = s & 1023;
  float v = frames[(c * 32 + g) * 2048 + j0];
  if (g > 0) v += frames[(c * 32 + g - 1) * 2048 + j0 + 1024];
  res[i] = v;
}

// ---------------- B-pack: res -> bf16 hi/lo in MFMA b-fragment layout ----------------
__global__ __launch_bounds__(256) void k_bpack(const float* __restrict__ res,
                                               short* __restrict__ Bh,
                                               short* __restrict__ Bl) {
  int c = blockIdx.x >> 4, o = blockIdx.x & 15;
  int r = threadIdx.x;
  bf16x8 hv, lv;
#pragma unroll
  for (int j = 0; j < 8; ++j) {
    float val = res[c * 32768 + (8 * o + j) * 256 + r];
    unsigned bits = __float_as_uint(val);
    float rem = val - __uint_as_float(bits & 0xffff0000u);
    hv[j] = (short)(bits >> 16);
    lv[j] = (short)(__float_as_uint(rem) >> 16);
  }
  int unit = (blockIdx.x * 16 + (r >> 4)) * 16 + (r & 15);
  ((bf16x8*)Bh)[unit] = hv;
  ((bf16x8*)Bl)[unit] = lv;
}

// ---------------- final conv as MFMA GEMM with 4x B-reuse ----------------
// v2: block = (b-pair, qt-pair j, uc). M = 2 batches x 32 Q-rows, N = 256 r,
// K = 512 (32 c x 16 u) done in two c-phases of 256 that re-use one 68 KB
// hi/lo-split A buffer in LDS (total ~78 KB -> 2 blocks/CU). Each wave owns 4
// nt-columns and feeds every loaded B fragment pair to all 4 (b, qtsub) A-tiles
// (12 MFMA per 2 global b128 loads), cutting B-side L2 read traffic 3.6x
// (590 MB -> 168 MB) vs the 1-tile-per-block version. Grid = 16 b2 x 20 (j,uc)
// = 320 equal-cost blocks, all co-resident at 2/CU. uc = 2j+1 items have a
// zeroed qt=2j half-tile (vwin range check), so coverage = exact triangle.
// Fragment maps identical to the validated v1: A[m=l15][k=quad*8+j],
// B[n=l15][k=quad*8+j], D row=quad*4+reg, col=l15.
__global__ __launch_bounds__(256, 2) void k_conv(const float* __restrict__ v,
                                                 const short* __restrict__ Bh,
                                                 const short* __restrict__ Bl,
                                                 float* __restrict__ y) {
  __shared__ __align__(16) short AH[2 * 32 * 264];   // [bb][row 32][K 256 + pad 8]
  __shared__ __align__(16) short AL[2 * 32 * 264];
  __shared__ float vwin[2][2][16][48];               // [bb][c-half][c_local][ii]

  int blk = blockIdx.x;            // 320 = 16 b-pairs * 20 (j,uc) items
  int b2 = blk / 20;
  int e  = blk - b2 * 20;
  int j, uc;
  if      (e < 2)  { j = 0; uc = e; }
  else if (e < 6)  { j = 1; uc = e - 2; }
  else if (e < 12) { j = 2; uc = e - 6; }
  else             { j = 3; uc = e - 12; }
  int D0 = 32 * j - 16 * uc;       // d = D0 - 15 + ii, ii in [0,46]

  // stage compact v windows (both b, both c-halves): 2*2*16*47 floats
  for (int i = threadIdx.x; i < 3008; i += 256) {
    int ii = i % 47;
    int r  = i / 47;
    int c  = r & 15, p = (r >> 4) & 1, bbv = r >> 5;
    int d  = D0 - 15 + ii;
    vwin[bbv][p][c][ii] = (d >= 0 && d < 128)
        ? v[(2 * b2 + bbv) * 4096 + (16 * p + c) * 128 + d] : 0.f;
  }
  __syncthreads();

  int lane = threadIdx.x & 63, wave = threadIdx.x >> 6;
  int quad = lane >> 4, l15 = lane & 15;
  int cq   = quad >> 1;            // low bit of c
  int og   = 2 * uc + (quad & 1);  // global u-octet
  int nt0  = wave * 4;

  f32x4 acc[4][4];                 // [tile = bb*2+qtsub][t]
#pragma unroll
  for (int a = 0; a < 4; ++a)
#pragma unroll
    for (int t = 0; t < 4; ++t) acc[a][t] = (f32x4)0.f;

  const bf16x8* AH8 = (const bf16x8*)AH;
  const bf16x8* AL8 = (const bf16x8*)AL;
  const bf16x8* Bh8 = (const bf16x8*)Bh;
  const bf16x8* Bl8 = (const bf16x8*)Bl;
  short2* AH2 = (short2*)AH;
  short2* AL2 = (short2*)AL;

  int abase[4];
#pragma unroll
  for (int bbi = 0; bbi < 2; ++bbi)
#pragma unroll
    for (int qs = 0; qs < 2; ++qs)
      abase[bbi * 2 + qs] = (bbi * 32 + qs * 16 + l15) * 33 + quad;  // bf16x8 units

  for (int p = 0; p < 2; ++p) {
    // expand Toeplitz A (hi/lo split) for this c-half: 2b x 32row x 128 kk-pairs
    for (int i = threadIdx.x; i < 8192; i += 256) {
      int kk2 = i & 127;           // kk = 2*kk2 (pair shares c_local)
      int row = (i >> 7) & 31;
      int bbv = i >> 12;
      int cl  = kk2 >> 3;
      int uu  = (kk2 & 7) * 2;
      int ii  = row - uu + 15;
      float v0 = vwin[bbv][p][cl][ii];
      float v1 = vwin[bbv][p][cl][ii - 1];
      unsigned w0 = __float_as_uint(v0), w1 = __float_as_uint(v1);
      float r0 = v0 - __uint_as_float(w0 & 0xffff0000u);
      float r1 = v1 - __uint_as_float(w1 & 0xffff0000u);
      int u2 = (bbv * 32 + row) * 132 + kk2;   // short2 units, row stride 132
      AH2[u2] = make_short2((short)(w0 >> 16), (short)(w1 >> 16));
      AL2[u2] = make_short2((short)(__float_as_uint(r0) >> 16),
                            (short)(__float_as_uint(r1) >> 16));
    }
    __syncthreads();

#pragma unroll
    for (int ks = 0; ks < 8; ++ks) {
      bf16x8 ah[4], al[4];
#pragma unroll
      for (int tl = 0; tl < 4; ++tl) {
        ah[tl] = AH8[abase[tl] + ks * 4];
        al[tl] = AL8[abase[tl] + ks * 4];
      }
      int c = 16 * p + 2 * ks + cq;
      int bb0 = (c * 16 + og) * 256 + l15;
#pragma unroll
      for (int t = 0; t < 4; ++t) {
        int bi = bb0 + (nt0 + t) * 16;
        bf16x8 bvh = Bh8[bi];
        bf16x8 bvl = Bl8[bi];
#pragma unroll
        for (int tl = 0; tl < 4; ++tl) {
          MFMA16(acc[tl][t], ah[tl], bvh);
          MFMA16(acc[tl][t], ah[tl], bvl);
          MFMA16(acc[tl][t], al[tl], bvh);
        }
      }
    }
    __syncthreads();               // A consumed; safe to overwrite in next phase
  }

#pragma unroll
  for (int bbi = 0; bbi < 2; ++bbi)
#pragma unroll
    for (int qs = 0; qs < 2; ++qs) {
      float* yb = y + (2 * b2 + bbi) * 32768
                    + (32 * j + qs * 16 + quad * 4) * 256 + l15;
#pragma unroll
      for (int t = 0; t < 4; ++t)
#pragma unroll
        for (int reg = 0; reg < 4; ++reg)
          atomicAdd(yb + reg * 256 + (nt0 + t) * 16, acc[bbi * 2 + qs][t][reg]);
    }
}

extern "C" void kernel_launch(void* const* d_in, const int* in_sizes, int n_in,
                              void* d_out, int out_size, void* d_ws, size_t ws_size,
                              hipStream_t stream) {
  const float* audio = (const float*)d_in[0];
  const float* Win   = (const float*)d_in[1];
  const float* bin   = (const float*)d_in[2];
  const float* bw    = (const float*)d_in[3];
  const float* bb    = (const float*)d_in[4];
  const float* Ws    = (const float*)d_in[5];
  const float* bs    = (const float*)d_in[6];
  const float* Wd    = (const float*)d_in[7];
  const float* bd    = (const float*)d_in[8];
  const float* reson = (const float*)d_in[9];

  float* out = (float*)d_out;           // [0,1048576) = y ; [1048576,2097152) = sparse
  float* ws  = (float*)d_ws;

  float* spec   = ws + WS_SPEC;
  float* h0     = ws + WS_H0;
  float* accb   = ws + WS_ACC;
  float* vbuf   = ws + WS_V;
  float* WT     = ws + WS_WTIN;
  float* WsT    = ws + WS_WST;
  float* WdT    = ws + WS_WDT;
  float* frames = ws + WS_FRAMES;
  float* resbuf = ws + WS_RES;
  // frames region is dead after k_res_assemble -> reuse for bf16 B packs
  short* Bh = (short*)(ws + WS_FRAMES);            // 1,048,576 bf16 = 2 MB
  short* Bl = (short*)(ws + WS_FRAMES + 524288u);  // 1,048,576 bf16 = 2 MB
  // chain-weight packs live in WS_V until k_sparse_dense overwrites it (after k_chain)
  short* Whg = (short*)(ws + WS_V);                // 16384 bf16 = 32 KB
  short* Wlg = (short*)(ws + WS_V + 8192u);        // 16384 bf16 = 32 KB

  // zero y region (atomicAdd target); d_out is poisoned before every launch
  hipMemsetAsync(d_out, 0, 1048576u * sizeof(float), stream);

  k_prep<<<128, 256, 0, stream>>>(Win, Ws, Wd, bw, WT, WsT, WdT, Whg, Wlg);
  k_fft<<<2560, 256, 0, stream>>>(audio, reson, spec, frames);
  k_res_assemble<<<4096, 256, 0, stream>>>(frames, resbuf);
  k_bpack<<<512, 256, 0, stream>>>(resbuf, Bh, Bl);
  k_proj_in<<<512, 256, 0, stream>>>(spec, WT, bin, h0);
  k_chain<<<32, 1024, 0, stream>>>(h0, Whg, Wlg, bb, accb);
  k_sparse_dense<<<4096, 256, 0, stream>>>(accb, WsT, bs, WdT, bd, out + 1048576, vbuf);
  k_conv<<<320, 256, 0, stream>>>(vbuf, Bh, Bl, out);
}

// Round 2
// 202.706 us; speedup vs baseline: 1.0616x; 1.0616x over previous
//
#include <hip/hip_runtime.h>

#define PI_F 3.14159265358979323846f

typedef short bf16x8 __attribute__((ext_vector_type(8)));
typedef float f32x4 __attribute__((ext_vector_type(4)));

#define MFMA16(acc, a, b) \
  acc = __builtin_amdgcn_mfma_f32_16x16x32_bf16(a, b, acc, 0, 0, 0)

// ---------------- workspace layout (float offsets) ----------------
#define WS_SPEC   0u          // 32*128*1024  [b][t][k]
#define WS_H0     4194304u    // 32*32*128    [b][o][t]
#define WS_ACC    4325376u    // 32*128*32    [b][t][o]
#define WS_V      4456448u    // 32*32*128    [b][c][t]; ALSO: k_prep stashes the
                              // chain-weight bf16 packs in the first 16384 floats
                              // (region only becomes v after k_sparse_dense,
                              // which runs after k_chain has consumed the packs)
#define WS_WTIN   4587520u    // 1024*32      [k][o]
#define WS_WST    4620288u    // 32*256       [m][o2]
#define WS_WDT    4628480u    // 256*32       [o2][c]
#define WS_FRAMES 4636672u    // 32*32*2048   [c][f][j]; after k_res_assemble this
                              // region is DEAD -> reused for Bh/Bl bf16 packs
#define WS_RES    6733824u    // 32*32768     [c][s]
// total 7782400 floats = ~29.7 MB

// ---- 2048-pt complex DIT FFT, input already in bit-reversed order, 256 thr ----
__device__ __forceinline__ void fft2048_stages(float2* buf, int tid) {
  for (int stage = 0; stage < 11; ++stage) {
    int half = 1 << stage;
    float base = -PI_F / (float)half;   // -2*pi/len
    for (int t = tid; t < 1024; t += 256) {
      int j  = t & (half - 1);
      int i0 = ((t >> stage) << (stage + 1)) + j;
      int i1 = i0 + half;
      float s, c;
      __sincosf(base * (float)j, &s, &c);   // e^{-i*2pi/len*j} = c + i*s
      float2 u = buf[i0];
      float2 w = buf[i1];
      float tr = c * w.x - s * w.y;
      float ti = c * w.y + s * w.x;
      buf[i0] = make_float2(u.x + tr, u.y + ti);
      buf[i1] = make_float2(u.x - tr, u.y - ti);
    }
    __syncthreads();
  }
}

// ---------------- fused FFT kernel: STFT pairs + resonance-frame pairs ----------------
__global__ __launch_bounds__(256) void k_fft(const float* __restrict__ audio,
                                             const float* __restrict__ resin,
                                             float* __restrict__ spec,
                                             float* __restrict__ frames) {
  __shared__ float2 buf[2048];
  int blk = blockIdx.x;
  if (blk < 2048) {
    int b  = blk >> 6;
    int f0 = (blk & 63) * 2;      // frames f0, f0+1
    for (int j = threadIdx.x; j < 2048; j += 256) {
      float h = 0.5f - 0.5f * __cosf(0.0030679615757712823f * (float)j); // 2pi/2048
      int i1 = f0 * 256 + j;
      int i2 = i1 + 256;
      float a1 = (i1 < 32768) ? audio[b * 32768 + i1] : 0.f;
      float a2 = (i2 < 32768) ? audio[b * 32768 + i2] : 0.f;
      buf[__brev((unsigned)j) >> 21] = make_float2(a1 * h, a2 * h);
    }
    __syncthreads();
    fft2048_stages(buf, threadIdx.x);
    const float scale = 0.5f * 0.022097086912079608f;  // 0.5 / sqrt(2048)
    for (int k = threadIdx.x; k < 1024; k += 256) {
      float2 zk = buf[k];
      float2 zn = buf[(2048 - k) & 2047];
      float f1r = zk.x + zn.x, f1i = zk.y - zn.y;
      float f2r = zk.y + zn.y, f2i = zk.x - zn.x;
      spec[(b * 128 + f0) * 1024 + k]     = sqrtf(f1r * f1r + f1i * f1i) * scale;
      spec[(b * 128 + f0 + 1) * 1024 + k] = sqrtf(f2r * f2r + f2i * f2i) * scale;
    }
  } else {
    int r = blk - 2048;           // 0..511
    int c = r >> 4;
    int g = r & 15;               // frames 2g (exp 2g+1), 2g+1 (exp 2g+2)
    float e1 = (float)(2 * g + 1);
    for (int k = threadIdx.x; k < 2048; k += 256) {
      int kk = (k <= 1024) ? k : 2048 - k;   // Hermitian (real) extension
      float cv = resin[c * 1025 + kk];
      cv = fminf(fmaxf(cv, 0.f), 0.9999f);
      float m1 = __powf(cv, e1);
      float m2 = m1 * cv;
      buf[__brev((unsigned)k) >> 21] = make_float2(m1, m2);
    }
    __syncthreads();
    fft2048_stages(buf, threadIdx.x);
    for (int j = threadIdx.x; j < 2048; j += 256) {
      float h  = 0.5f - 0.5f * __cosf(0.0030679615757712823f * (float)j);
      float sc = h * (1.f / 2048.f);
      float2 z = buf[j];
      frames[(c * 32 + 2 * g) * 2048 + j]     = z.x * sc;
      frames[(c * 32 + 2 * g + 1) * 2048 + j] = z.y * sc;
    }
  }
}

// ---------------- weight transposes + chain-weight bf16 hi/lo packs ----------------
// Chain pack layout (B-fragment-native): row = (s*2 + which)*32 + o, 32 bf16/row;
// lane loads b128 at row*32 + quad*8 -> B[n=o][k=quad*8+j] for mfma.
__global__ __launch_bounds__(256) void k_prep(const float* __restrict__ Win,
                                              const float* __restrict__ Ws,
                                              const float* __restrict__ Wd,
                                              const float* __restrict__ bwIn,
                                              float* __restrict__ WT,
                                              float* __restrict__ WsT,
                                              float* __restrict__ WdT,
                                              short* __restrict__ Whg,
                                              short* __restrict__ Wlg) {
  int i = blockIdx.x * 256 + threadIdx.x;
  if (i < 32768) { int o = i >> 10, k = i & 1023; WT[k * 32 + o] = Win[i]; }
  if (i < 8192)  { int o2 = i >> 5, m = i & 31;   WsT[m * 256 + o2] = Ws[i]; }
  if (i < 8192)  { int c = i >> 8, o2 = i & 255;  WdT[o2 * 32 + c] = Wd[i]; }
  if (i < 16384) {
    // i = ((s*32+o)*32+m)*2 + w
    int w = i & 1, m = (i >> 1) & 31, o = (i >> 6) & 31, s = i >> 11;
    float val = bwIn[i];
    unsigned bits = __float_as_uint(val);
    float rem = val - __uint_as_float(bits & 0xffff0000u);
    int row = (s * 2 + w) * 32 + o;
    Whg[row * 32 + m] = (short)(bits >> 16);
    Wlg[row * 32 + m] = (short)(__float_as_uint(rem) >> 16);
  }
}

// ---------------- proj_in: h0[b,o,t] = sum_k WT[k][o]*spec[b,t,k] + bias ----------------
__global__ __launch_bounds__(256) void k_proj_in(const float* __restrict__ spec,
                                                 const float* __restrict__ WT,
                                                 const float* __restrict__ bias,
                                                 float* __restrict__ h0) {
  __shared__ float specL[8][1024];
  __shared__ float red[32][8][8];   // [o][tt][p]
  int b  = blockIdx.x >> 4;
  int t0 = (blockIdx.x & 15) * 8;
  for (int i = threadIdx.x; i < 8192; i += 256) {
    int tt = i >> 10, k = i & 1023;
    specL[tt][k] = spec[(b * 128 + t0 + tt) * 1024 + k];
  }
  __syncthreads();
  int o = threadIdx.x & 31, p = threadIdx.x >> 5;
  float part[8] = {0.f,0.f,0.f,0.f,0.f,0.f,0.f,0.f};
  for (int i = 0; i < 128; ++i) {
    int k = p * 128 + ((i + p * 4) & 127);   // stagger: conflict-free banks across p
    float w = WT[k * 32 + o];
#pragma unroll
    for (int tt = 0; tt < 8; ++tt) part[tt] += w * specL[tt][k];
  }
#pragma unroll
  for (int tt = 0; tt < 8; ++tt) red[o][tt][p] = part[tt];
  __syncthreads();
  int oo = threadIdx.x >> 3, tt2 = threadIdx.x & 7;
  float s = bias[oo];
#pragma unroll
  for (int p2 = 0; p2 < 8; ++p2) s += red[oo][tt2][p2];
  h0[b * 4096 + oo * 128 + t0 + tt2] = s;
}

// ---------------- 8-block anticausal chain as per-step MFMA GEMM pairs ----------------
// One block per batch (serial dependency: per-step global max). Per step:
// Y[128t x 32o] = H^T W0^T + Hshift^T W1^T + bias -> 16 waves x one 16x16 tile,
// 6 MFMA each (bf16 hi/lo split: AhBh + AhBl + AlBh per W). H stored in LDS as
// split-bf16 [t][ch] rows (b128 A-frag reads; rows 128..191 zeroed so the
// anticausal shift t+d reads zeros). Fragment maps identical to k_conv
// (validated): A[m=lane&15][k=quad*8+j], B[n=lane&15][k=quad*8+j],
// D row=quad*4+reg (t), col=lane&15 (o). Max-reduce: wave shuffle -> red[16] ->
// every thread folds 16 values (no serial section). 2 barriers/step.
__global__ __launch_bounds__(1024) void k_chain(const float* __restrict__ h0,
                                                const short* __restrict__ Whg,
                                                const short* __restrict__ Wlg,
                                                const float* __restrict__ bb,
                                                float* __restrict__ accout) {
  __shared__ __align__(16) short Hh[192 * 40];   // rows stride 40 bf16 (80 B)
  __shared__ __align__(16) short Hl[192 * 40];
  __shared__ float Hf[128 * 33];                 // fp32 H for exact residual
  __shared__ float bL[256];
  __shared__ float red[16];
  int b = blockIdx.x, tid = threadIdx.x;

  for (int i = tid; i < 4096; i += 1024) {
    int t = i & 127;                 // h0 layout [o][t]
    int o = i >> 7;
    float val = h0[b * 4096 + i];
    Hf[t * 33 + o] = val;
    unsigned bits = __float_as_uint(val);
    float rem = val - __uint_as_float(bits & 0xffff0000u);
    Hh[t * 40 + o] = (short)(bits >> 16);
    Hl[t * 40 + o] = (short)(__float_as_uint(rem) >> 16);
  }
  for (int i = tid; i < 64 * 40; i += 1024) {    // zero pad rows 128..191
    Hh[128 * 40 + i] = 0;
    Hl[128 * 40 + i] = 0;
  }
  if (tid < 256) bL[tid] = bb[tid];
  __syncthreads();

  int wave = tid >> 6, lane = tid & 63;
  int quad = lane >> 4, l15 = lane & 15;
  int t0 = (wave & 7) * 16, o0 = (wave >> 3) * 16;
  int tD = t0 + quad * 4;          // D rows tD..tD+3
  int oD = o0 + l15;               // D col

  const bf16x8* Hh8 = (const bf16x8*)Hh;   // unit = row*5 + quad (40 bf16 = 5 units)
  const bf16x8* Hl8 = (const bf16x8*)Hl;
  const bf16x8* Wh8 = (const bf16x8*)Whg;  // unit = row*4 + quad (32 bf16 = 4 units)
  const bf16x8* Wl8 = (const bf16x8*)Wlg;

  float accsum[4] = {0.f, 0.f, 0.f, 0.f};
  const int DIL[8] = {1, 2, 4, 8, 16, 32, 64, 1};

#pragma unroll
  for (int s = 0; s < 8; ++s) {
    int arow = t0 + l15;
    int frow = arow + DIL[s];        // <= 191, pad rows give zeros
    bf16x8 Ah = Hh8[arow * 5 + quad];
    bf16x8 Al = Hl8[arow * 5 + quad];
    bf16x8 Fh = Hh8[frow * 5 + quad];
    bf16x8 Fl = Hl8[frow * 5 + quad];
    int w0row = ((s * 2 + 0) * 32 + oD) * 4 + quad;
    int w1row = ((s * 2 + 1) * 32 + oD) * 4 + quad;
    bf16x8 B0h = Wh8[w0row], B0l = Wl8[w0row];
    bf16x8 B1h = Wh8[w1row], B1l = Wl8[w1row];
    float bias = bL[s * 32 + oD];
    f32x4 acc = {bias, bias, bias, bias};
    MFMA16(acc, Ah, B0h); MFMA16(acc, Ah, B0l); MFMA16(acc, Al, B0h);
    MFMA16(acc, Fh, B1h); MFMA16(acc, Fh, B1l); MFMA16(acc, Fl, B1h);
    float hnew[4], lmax = 0.f;
#pragma unroll
    for (int r = 0; r < 4; ++r) {
      float sv = acc[r];
      sv = (sv > 0.f) ? sv : 0.2f * sv;       // leaky_relu 0.2
      sv += Hf[(tD + r) * 33 + oD];           // residual (exact fp32)
      hnew[r] = sv;
      lmax = fmaxf(lmax, fabsf(sv));
    }
#pragma unroll
    for (int off = 32; off > 0; off >>= 1)
      lmax = fmaxf(lmax, __shfl_down(lmax, off, 64));
    if (lane == 0) red[wave] = lmax;
    __syncthreads();                 // red visible; all H reads of this step done
    float mx = red[0];
#pragma unroll
    for (int i = 1; i < 16; ++i) mx = fmaxf(mx, red[i]);
    float nm = 1.f / (mx + 1e-8f);
#pragma unroll
    for (int r = 0; r < 4; ++r) {
      float hv = hnew[r] * nm;
      accsum[r] += hv;
      int t = tD + r;
      Hf[t * 33 + oD] = hv;
      unsigned bits = __float_as_uint(hv);
      float rem = hv - __uint_as_float(bits & 0xffff0000u);
      Hh[t * 40 + oD] = (short)(bits >> 16);
      Hl[t * 40 + oD] = (short)(__float_as_uint(rem) >> 16);
    }
    __syncthreads();                 // new H visible for next step
  }
#pragma unroll
  for (int r = 0; r < 4; ++r)
    accout[b * 4096 + (tD + r) * 32 + oD] = accsum[r];
}

// ---------------- sparse (relu proj 32->256, to d_out) + dense (256->32, to ws) ----------------
__global__ __launch_bounds__(256) void k_sparse_dense(const float* __restrict__ acc,
                                                      const float* __restrict__ WsT,
                                                      const float* __restrict__ bs,
                                                      const float* __restrict__ WdT,
                                                      const float* __restrict__ bd,
                                                      float* __restrict__ out_sparse,
                                                      float* __restrict__ v) {
  __shared__ float accL[32];
  __shared__ float sL[256];
  __shared__ float red[8][32];
  int b = blockIdx.x >> 7, t = blockIdx.x & 127;
  int tid = threadIdx.x;
  if (tid < 32) accL[tid] = acc[b * 4096 + t * 32 + tid];
  __syncthreads();
  float s = bs[tid];
  for (int m = 0; m < 32; ++m) s += WsT[m * 256 + tid] * accL[m];
  s = fmaxf(s, 0.f);
  out_sparse[b * 32768 + tid * 128 + t] = s;
  sL[tid] = s;
  __syncthreads();
  int c = tid & 31, p = tid >> 5;
  float part = 0.f;
  for (int j = 0; j < 32; ++j) {
    int o2 = p * 32 + j;
    part += WdT[o2 * 32 + c] * sL[o2];
  }
  red[p][c] = part;
  __syncthreads();
  if (tid < 32) {
    float vv = bd[tid];
    for (int p2 = 0; p2 < 8; ++p2) vv += red[p2][tid];
    v[b * 4096 + tid * 128 + t] = vv;
  }
}

// ---------------- overlap-add (hop 1024): at most 2 frames per sample ----------------
__global__ __launch_bounds__(256) void k_res_assemble(const float* __restrict__ frames,
                                                      float* __restrict__ res) {
  int i = blockIdx.x * 256 + threadIdx.x;   // 0 .. 32*32768
  int c = i >> 15, s = i & 32767;
  int g = s >> 10, j0 = s & 1023;
  float v = frames[(c * 32 + g) * 2048 + j0];
  if (g > 0) v += frames[(c * 32 + g - 1) * 2048 + j0 + 1024];
  res[i] = v;
}

// ---------------- B-pack: res -> bf16 hi/lo in MFMA b-fragment layout ----------------
__global__ __launch_bounds__(256) void k_bpack(const float* __restrict__ res,
                                               short* __restrict__ Bh,
                                               short* __restrict__ Bl) {
  int c = blockIdx.x >> 4, o = blockIdx.x & 15;
  int r = threadIdx.x;
  bf16x8 hv, lv;
#pragma unroll
  for (int j = 0; j < 8; ++j) {
    float val = res[c * 32768 + (8 * o + j) * 256 + r];
    unsigned bits = __float_as_uint(val);
    float rem = val - __uint_as_float(bits & 0xffff0000u);
    hv[j] = (short)(bits >> 16);
    lv[j] = (short)(__float_as_uint(rem) >> 16);
  }
  int unit = (blockIdx.x * 16 + (r >> 4)) * 16 + (r & 15);
  ((bf16x8*)Bh)[unit] = hv;
  ((bf16x8*)Bl)[unit] = lv;
}

// ---------------- final conv as MFMA GEMM, v3: occupancy-first ----------------
// Post-mortem of v2: B-reuse-4 worked (FETCH 15->8.4 MB) but grid 320 x 4 waves
// = 0.9-1.25 waves/SIMD could not hide L2 latency -> same 44 us as v1. k_conv is
// LATENCY-bound, not traffic-bound. v3 re-balances: block = (b, qt-pair j, uc),
// grid 640, 512 threads = 8 waves (each wave 2 nt-columns), LDS ~39 KB
// (A 32rows x 256K hi/lo per c-phase + vwin) -> 2 blocks/CU at <=128 VGPR =
// 16 waves/CU = 4 waves/SIMD (~4x v2). B-reuse = 2 (qs pair shares every B
// fragment): ~295 MB L2 reads, BW floor ~12 us. acc = 2qs x 2nt x f32x4 = 16
// VGPRs -> compiler has headroom to keep all 4 B pairs of a ks in flight.
// Fragment maps identical to validated v1/v2: A[m=l15][k=quad*8+j],
// B[n=l15][k=quad*8+j], D row=quad*4+reg, col=l15; c = 16p+2ks+(quad>>1),
// u-octet og = 2uc+(quad&1). uc = 2j+1 items: qs=0 half-tile is all-zero via
// vwin range clamp (d<0) -> exact triangle coverage.
__global__ __launch_bounds__(512, 4) void k_conv(const float* __restrict__ v,
                                                 const short* __restrict__ Bh,
                                                 const short* __restrict__ Bl,
                                                 float* __restrict__ y) {
  __shared__ __align__(16) short AH[32 * 264];   // [row 32][K 256 + pad 8]
  __shared__ __align__(16) short AL[32 * 264];
  __shared__ float vwin[2][16][48];              // [c-half][c_local][ii]

  int blk = blockIdx.x;            // 640 = 32 b * 20 (j,uc) items
  int b = blk / 20;
  int e = blk - b * 20;
  int j, uc;
  if      (e < 2)  { j = 0; uc = e; }
  else if (e < 6)  { j = 1; uc = e - 2; }
  else if (e < 12) { j = 2; uc = e - 6; }
  else             { j = 3; uc = e - 12; }
  int D0 = 32 * j - 16 * uc;       // d = D0 - 15 + ii, ii in [0,46]

  // stage compact v windows (both c-halves): 2*16*47 floats
  for (int i = threadIdx.x; i < 1504; i += 512) {
    int ii = i % 47;
    int r  = i / 47;               // 0..31
    int c  = r & 15, p = r >> 4;
    int d  = D0 - 15 + ii;
    vwin[p][c][ii] = (d >= 0 && d < 128)
        ? v[b * 4096 + (16 * p + c) * 128 + d] : 0.f;
  }
  __syncthreads();

  int lane = threadIdx.x & 63, wave = threadIdx.x >> 6;
  int quad = lane >> 4, l15 = lane & 15;
  int cq   = quad >> 1;            // low bit of c
  int og   = 2 * uc + (quad & 1);  // global u-octet
  int nt0  = wave * 2;             // 8 waves x 2 nt = 16 nt

  f32x4 acc00 = (f32x4)0.f, acc01 = (f32x4)0.f;   // [qs][t]
  f32x4 acc10 = (f32x4)0.f, acc11 = (f32x4)0.f;

  const bf16x8* AH8 = (const bf16x8*)AH;
  const bf16x8* AL8 = (const bf16x8*)AL;
  const bf16x8* Bh8 = (const bf16x8*)Bh;
  const bf16x8* Bl8 = (const bf16x8*)Bl;
  short2* AH2 = (short2*)AH;
  short2* AL2 = (short2*)AL;

  int abase0 = (0 * 16 + l15) * 33 + quad;   // bf16x8 units, row stride 33
  int abase1 = (1 * 16 + l15) * 33 + quad;

  for (int p = 0; p < 2; ++p) {
    // expand Toeplitz A (hi/lo split) for this c-half: 32 rows x 128 kk-pairs
    for (int i = threadIdx.x; i < 4096; i += 512) {
      int kk2 = i & 127;           // kk = 2*kk2 (pair shares c_local)
      int row = i >> 7;            // 0..31
      int cl  = kk2 >> 3;
      int uu  = (kk2 & 7) * 2;
      int ii  = row - uu + 15;
      float v0 = vwin[p][cl][ii];
      float v1 = vwin[p][cl][ii - 1];
      unsigned w0 = __float_as_uint(v0), w1 = __float_as_uint(v1);
      float r0 = v0 - __uint_as_float(w0 & 0xffff0000u);
      float r1 = v1 - __uint_as_float(w1 & 0xffff0000u);
      int u2 = row * 132 + kk2;    // short2 units, row stride 132
      AH2[u2] = make_short2((short)(w0 >> 16), (short)(w1 >> 16));
      AL2[u2] = make_short2((short)(__float_as_uint(r0) >> 16),
                            (short)(__float_as_uint(r1) >> 16));
    }
    __syncthreads();

#pragma unroll
    for (int ks = 0; ks < 8; ++ks) {
      bf16x8 ah0 = AH8[abase0 + ks * 4];
      bf16x8 al0 = AL8[abase0 + ks * 4];
      bf16x8 ah1 = AH8[abase1 + ks * 4];
      bf16x8 al1 = AL8[abase1 + ks * 4];
      int c   = 16 * p + 2 * ks + cq;
      int bb0 = (c * 16 + og) * 256 + l15;
      bf16x8 bh0 = Bh8[bb0 + nt0 * 16];
      bf16x8 bl0 = Bl8[bb0 + nt0 * 16];
      bf16x8 bh1 = Bh8[bb0 + (nt0 + 1) * 16];
      bf16x8 bl1 = Bl8[bb0 + (nt0 + 1) * 16];
      MFMA16(acc00, ah0, bh0); MFMA16(acc00, ah0, bl0); MFMA16(acc00, al0, bh0);
      MFMA16(acc10, ah1, bh0); MFMA16(acc10, ah1, bl0); MFMA16(acc10, al1, bh0);
      MFMA16(acc01, ah0, bh1); MFMA16(acc01, ah0, bl1); MFMA16(acc01, al0, bh1);
      MFMA16(acc11, ah1, bh1); MFMA16(acc11, ah1, bl1); MFMA16(acc11, al1, bh1);
    }
    __syncthreads();               // A consumed; safe to overwrite in next phase
  }

  {
    float* yb0 = y + b * 32768 + (32 * j + 0 * 16 + quad * 4) * 256 + l15;
    float* yb1 = y + b * 32768 + (32 * j + 1 * 16 + quad * 4) * 256 + l15;
#pragma unroll
    for (int reg = 0; reg < 4; ++reg) {
      atomicAdd(yb0 + reg * 256 + (nt0 + 0) * 16, acc00[reg]);
      atomicAdd(yb0 + reg * 256 + (nt0 + 1) * 16, acc01[reg]);
      atomicAdd(yb1 + reg * 256 + (nt0 + 0) * 16, acc10[reg]);
      atomicAdd(yb1 + reg * 256 + (nt0 + 1) * 16, acc11[reg]);
    }
  }
}

extern "C" void kernel_launch(void* const* d_in, const int* in_sizes, int n_in,
                              void* d_out, int out_size, void* d_ws, size_t ws_size,
                              hipStream_t stream) {
  const float* audio = (const float*)d_in[0];
  const float* Win   = (const float*)d_in[1];
  const float* bin   = (const float*)d_in[2];
  const float* bw    = (const float*)d_in[3];
  const float* bb    = (const float*)d_in[4];
  const float* Ws    = (const float*)d_in[5];
  const float* bs    = (const float*)d_in[6];
  const float* Wd    = (const float*)d_in[7];
  const float* bd    = (const float*)d_in[8];
  const float* reson = (const float*)d_in[9];

  float* out = (float*)d_out;           // [0,1048576) = y ; [1048576,2097152) = sparse
  float* ws  = (float*)d_ws;

  float* spec   = ws + WS_SPEC;
  float* h0     = ws + WS_H0;
  float* accb   = ws + WS_ACC;
  float* vbuf   = ws + WS_V;
  float* WT     = ws + WS_WTIN;
  float* WsT    = ws + WS_WST;
  float* WdT    = ws + WS_WDT;
  float* frames = ws + WS_FRAMES;
  float* resbuf = ws + WS_RES;
  // frames region is dead after k_res_assemble -> reuse for bf16 B packs
  short* Bh = (short*)(ws + WS_FRAMES);            // 1,048,576 bf16 = 2 MB
  short* Bl = (short*)(ws + WS_FRAMES + 524288u);  // 1,048,576 bf16 = 2 MB
  // chain-weight packs live in WS_V until k_sparse_dense overwrites it (after k_chain)
  short* Whg = (short*)(ws + WS_V);                // 16384 bf16 = 32 KB
  short* Wlg = (short*)(ws + WS_V + 8192u);        // 16384 bf16 = 32 KB

  // zero y region (atomicAdd target); d_out is poisoned before every launch
  hipMemsetAsync(d_out, 0, 1048576u * sizeof(float), stream);

  k_prep<<<128, 256, 0, stream>>>(Win, Ws, Wd, bw, WT, WsT, WdT, Whg, Wlg);
  k_fft<<<2560, 256, 0, stream>>>(audio, reson, spec, frames);
  k_res_assemble<<<4096, 256, 0, stream>>>(frames, resbuf);
  k_bpack<<<512, 256, 0, stream>>>(resbuf, Bh, Bl);
  k_proj_in<<<512, 256, 0, stream>>>(spec, WT, bin, h0);
  k_chain<<<32, 1024, 0, stream>>>(h0, Whg, Wlg, bb, accb);
  k_sparse_dense<<<4096, 256, 0, stream>>>(accb, WsT, bs, WdT, bd, out + 1048576, vbuf);
  k_conv<<<640, 512, 0, stream>>>(vbuf, Bh, Bl, out);
}

// Round 3
// 189.450 us; speedup vs baseline: 1.1359x; 1.0700x over previous
//
#include <hip/hip_runtime.h>

#define PI_F 3.14159265358979323846f

typedef short bf16x8 __attribute__((ext_vector_type(8)));
typedef float f32x4 __attribute__((ext_vector_type(4)));

#define MFMA16(acc, a, b) \
  acc = __builtin_amdgcn_mfma_f32_16x16x32_bf16(a, b, acc, 0, 0, 0)

// ---------------- workspace layout (float offsets) ----------------
#define WS_SPEC   0u          // 32*128*1024  [b][t][k]
#define WS_H0     4194304u    // 32*32*128    [b][o][t]
#define WS_ACC    4325376u    // 32*128*32    [b][t][o]
#define WS_V      4456448u    // 32*32*128    [b][c][t]; ALSO: k_prep stashes the
                              // chain-weight bf16 packs in the first 16384 floats
                              // (region only becomes v after k_sparse_dense,
                              // which runs after k_chain has consumed the packs)
#define WS_WTIN   4587520u    // 1024*32      [k][o]
#define WS_WST    4620288u    // 32*256       [m][o2]
#define WS_WDT    4628480u    // 256*32       [o2][c]
#define WS_FRAMES 4636672u    // 32*32*2048   [c][f][j]
#define WS_RES    6733824u    // (dead: res assembly fused into k_obpack) -> Bh/Bl packs
// total 7782400 floats = ~29.7 MB

// ---- 2048-pt complex DIT FFT, input already in bit-reversed order, 256 thr ----
__device__ __forceinline__ void fft2048_stages(float2* buf, int tid) {
  for (int stage = 0; stage < 11; ++stage) {
    int half = 1 << stage;
    float base = -PI_F / (float)half;   // -2*pi/len
    for (int t = tid; t < 1024; t += 256) {
      int j  = t & (half - 1);
      int i0 = ((t >> stage) << (stage + 1)) + j;
      int i1 = i0 + half;
      float s, c;
      __sincosf(base * (float)j, &s, &c);   // e^{-i*2pi/len*j} = c + i*s
      float2 u = buf[i0];
      float2 w = buf[i1];
      float tr = c * w.x - s * w.y;
      float ti = c * w.y + s * w.x;
      buf[i0] = make_float2(u.x + tr, u.y + ti);
      buf[i1] = make_float2(u.x - tr, u.y - ti);
    }
    __syncthreads();
  }
}

// ---------------- fused FFT kernel: STFT pairs + resonance-frame pairs ----------------
__global__ __launch_bounds__(256) void k_fft(const float* __restrict__ audio,
                                             const float* __restrict__ resin,
                                             float* __restrict__ spec,
                                             float* __restrict__ frames) {
  __shared__ float2 buf[2048];
  int blk = blockIdx.x;
  if (blk < 2048) {
    int b  = blk >> 6;
    int f0 = (blk & 63) * 2;      // frames f0, f0+1
    for (int j = threadIdx.x; j < 2048; j += 256) {
      float h = 0.5f - 0.5f * __cosf(0.0030679615757712823f * (float)j); // 2pi/2048
      int i1 = f0 * 256 + j;
      int i2 = i1 + 256;
      float a1 = (i1 < 32768) ? audio[b * 32768 + i1] : 0.f;
      float a2 = (i2 < 32768) ? audio[b * 32768 + i2] : 0.f;
      buf[__brev((unsigned)j) >> 21] = make_float2(a1 * h, a2 * h);
    }
    __syncthreads();
    fft2048_stages(buf, threadIdx.x);
    const float scale = 0.5f * 0.022097086912079608f;  // 0.5 / sqrt(2048)
    for (int k = threadIdx.x; k < 1024; k += 256) {
      float2 zk = buf[k];
      float2 zn = buf[(2048 - k) & 2047];
      float f1r = zk.x + zn.x, f1i = zk.y - zn.y;
      float f2r = zk.y + zn.y, f2i = zk.x - zn.x;
      spec[(b * 128 + f0) * 1024 + k]     = sqrtf(f1r * f1r + f1i * f1i) * scale;
      spec[(b * 128 + f0 + 1) * 1024 + k] = sqrtf(f2r * f2r + f2i * f2i) * scale;
    }
  } else {
    int r = blk - 2048;           // 0..511
    int c = r >> 4;
    int g = r & 15;               // frames 2g (exp 2g+1), 2g+1 (exp 2g+2)
    float e1 = (float)(2 * g + 1);
    for (int k = threadIdx.x; k < 2048; k += 256) {
      int kk = (k <= 1024) ? k : 2048 - k;   // Hermitian (real) extension
      float cv = resin[c * 1025 + kk];
      cv = fminf(fmaxf(cv, 0.f), 0.9999f);
      float m1 = __powf(cv, e1);
      float m2 = m1 * cv;
      buf[__brev((unsigned)k) >> 21] = make_float2(m1, m2);
    }
    __syncthreads();
    fft2048_stages(buf, threadIdx.x);
    for (int j = threadIdx.x; j < 2048; j += 256) {
      float h  = 0.5f - 0.5f * __cosf(0.0030679615757712823f * (float)j);
      float sc = h * (1.f / 2048.f);
      float2 z = buf[j];
      frames[(c * 32 + 2 * g) * 2048 + j]     = z.x * sc;
      frames[(c * 32 + 2 * g + 1) * 2048 + j] = z.y * sc;
    }
  }
}

// ---------------- weight transposes + chain-weight bf16 hi/lo packs ----------------
__global__ __launch_bounds__(256) void k_prep(const float* __restrict__ Win,
                                              const float* __restrict__ Ws,
                                              const float* __restrict__ Wd,
                                              const float* __restrict__ bwIn,
                                              float* __restrict__ WT,
                                              float* __restrict__ WsT,
                                              float* __restrict__ WdT,
                                              short* __restrict__ Whg,
                                              short* __restrict__ Wlg) {
  int i = blockIdx.x * 256 + threadIdx.x;
  if (i < 32768) { int o = i >> 10, k = i & 1023; WT[k * 32 + o] = Win[i]; }
  if (i < 8192)  { int o2 = i >> 5, m = i & 31;   WsT[m * 256 + o2] = Ws[i]; }
  if (i < 8192)  { int c = i >> 8, o2 = i & 255;  WdT[o2 * 32 + c] = Wd[i]; }
  if (i < 16384) {
    // i = ((s*32+o)*32+m)*2 + w
    int w = i & 1, m = (i >> 1) & 31, o = (i >> 6) & 31, s = i >> 11;
    float val = bwIn[i];
    unsigned bits = __float_as_uint(val);
    float rem = val - __uint_as_float(bits & 0xffff0000u);
    int row = (s * 2 + w) * 32 + o;
    Whg[row * 32 + m] = (short)(bits >> 16);
    Wlg[row * 32 + m] = (short)(__float_as_uint(rem) >> 16);
  }
}

// ---------------- proj_in: h0[b,o,t] = sum_k WT[k][o]*spec[b,t,k] + bias ----------------
__global__ __launch_bounds__(256) void k_proj_in(const float* __restrict__ spec,
                                                 const float* __restrict__ WT,
                                                 const float* __restrict__ bias,
                                                 float* __restrict__ h0) {
  __shared__ float specL[8][1024];
  __shared__ float red[32][8][8];   // [o][tt][p]
  int b  = blockIdx.x >> 4;
  int t0 = (blockIdx.x & 15) * 8;
  for (int i = threadIdx.x; i < 8192; i += 256) {
    int tt = i >> 10, k = i & 1023;
    specL[tt][k] = spec[(b * 128 + t0 + tt) * 1024 + k];
  }
  __syncthreads();
  int o = threadIdx.x & 31, p = threadIdx.x >> 5;
  float part[8] = {0.f,0.f,0.f,0.f,0.f,0.f,0.f,0.f};
  for (int i = 0; i < 128; ++i) {
    int k = p * 128 + ((i + p * 4) & 127);   // stagger: conflict-free banks across p
    float w = WT[k * 32 + o];
#pragma unroll
    for (int tt = 0; tt < 8; ++tt) part[tt] += w * specL[tt][k];
  }
#pragma unroll
  for (int tt = 0; tt < 8; ++tt) red[o][tt][p] = part[tt];
  __syncthreads();
  int oo = threadIdx.x >> 3, tt2 = threadIdx.x & 7;
  float s = bias[oo];
#pragma unroll
  for (int p2 = 0; p2 < 8; ++p2) s += red[oo][tt2][p2];
  h0[b * 4096 + oo * 128 + t0 + tt2] = s;
}

// ---------------- 8-block anticausal chain as per-step MFMA GEMM pairs ----------------
__global__ __launch_bounds__(1024) void k_chain(const float* __restrict__ h0,
                                                const short* __restrict__ Whg,
                                                const short* __restrict__ Wlg,
                                                const float* __restrict__ bb,
                                                float* __restrict__ accout) {
  __shared__ __align__(16) short Hh[192 * 40];   // rows stride 40 bf16 (80 B)
  __shared__ __align__(16) short Hl[192 * 40];
  __shared__ float Hf[128 * 33];                 // fp32 H for exact residual
  __shared__ float bL[256];
  __shared__ float red[16];
  int b = blockIdx.x, tid = threadIdx.x;

  for (int i = tid; i < 4096; i += 1024) {
    int t = i & 127;                 // h0 layout [o][t]
    int o = i >> 7;
    float val = h0[b * 4096 + i];
    Hf[t * 33 + o] = val;
    unsigned bits = __float_as_uint(val);
    float rem = val - __uint_as_float(bits & 0xffff0000u);
    Hh[t * 40 + o] = (short)(bits >> 16);
    Hl[t * 40 + o] = (short)(__float_as_uint(rem) >> 16);
  }
  for (int i = tid; i < 64 * 40; i += 1024) {    // zero pad rows 128..191
    Hh[128 * 40 + i] = 0;
    Hl[128 * 40 + i] = 0;
  }
  if (tid < 256) bL[tid] = bb[tid];
  __syncthreads();

  int wave = tid >> 6, lane = tid & 63;
  int quad = lane >> 4, l15 = lane & 15;
  int t0 = (wave & 7) * 16, o0 = (wave >> 3) * 16;
  int tD = t0 + quad * 4;          // D rows tD..tD+3
  int oD = o0 + l15;               // D col

  const bf16x8* Hh8 = (const bf16x8*)Hh;   // unit = row*5 + quad (40 bf16 = 5 units)
  const bf16x8* Hl8 = (const bf16x8*)Hl;
  const bf16x8* Wh8 = (const bf16x8*)Whg;  // unit = row*4 + quad (32 bf16 = 4 units)
  const bf16x8* Wl8 = (const bf16x8*)Wlg;

  float accsum[4] = {0.f, 0.f, 0.f, 0.f};
  const int DIL[8] = {1, 2, 4, 8, 16, 32, 64, 1};

#pragma unroll
  for (int s = 0; s < 8; ++s) {
    int arow = t0 + l15;
    int frow = arow + DIL[s];        // <= 191, pad rows give zeros
    bf16x8 Ah = Hh8[arow * 5 + quad];
    bf16x8 Al = Hl8[arow * 5 + quad];
    bf16x8 Fh = Hh8[frow * 5 + quad];
    bf16x8 Fl = Hl8[frow * 5 + quad];
    int w0row = ((s * 2 + 0) * 32 + oD) * 4 + quad;
    int w1row = ((s * 2 + 1) * 32 + oD) * 4 + quad;
    bf16x8 B0h = Wh8[w0row], B0l = Wl8[w0row];
    bf16x8 B1h = Wh8[w1row], B1l = Wl8[w1row];
    float bias = bL[s * 32 + oD];
    f32x4 acc = {bias, bias, bias, bias};
    MFMA16(acc, Ah, B0h); MFMA16(acc, Ah, B0l); MFMA16(acc, Al, B0h);
    MFMA16(acc, Fh, B1h); MFMA16(acc, Fh, B1l); MFMA16(acc, Fl, B1h);
    float hnew[4], lmax = 0.f;
#pragma unroll
    for (int r = 0; r < 4; ++r) {
      float sv = acc[r];
      sv = (sv > 0.f) ? sv : 0.2f * sv;       // leaky_relu 0.2
      sv += Hf[(tD + r) * 33 + oD];           // residual (exact fp32)
      hnew[r] = sv;
      lmax = fmaxf(lmax, fabsf(sv));
    }
#pragma unroll
    for (int off = 32; off > 0; off >>= 1)
      lmax = fmaxf(lmax, __shfl_down(lmax, off, 64));
    if (lane == 0) red[wave] = lmax;
    __syncthreads();                 // red visible; all H reads of this step done
    float mx = red[0];
#pragma unroll
    for (int i = 1; i < 16; ++i) mx = fmaxf(mx, red[i]);
    float nm = 1.f / (mx + 1e-8f);
#pragma unroll
    for (int r = 0; r < 4; ++r) {
      float hv = hnew[r] * nm;
      accsum[r] += hv;
      int t = tD + r;
      Hf[t * 33 + oD] = hv;
      unsigned bits = __float_as_uint(hv);
      float rem = hv - __uint_as_float(bits & 0xffff0000u);
      Hh[t * 40 + oD] = (short)(bits >> 16);
      Hl[t * 40 + oD] = (short)(__float_as_uint(rem) >> 16);
    }
    __syncthreads();                 // new H visible for next step
  }
#pragma unroll
  for (int r = 0; r < 4; ++r)
    accout[b * 4096 + (tD + r) * 32 + oD] = accsum[r];
}

// ---------------- sparse + dense, 4 t per block (4x weight reuse + ILP) ----------------
__global__ __launch_bounds__(256) void k_sparse_dense(const float* __restrict__ acc,
                                                      const float* __restrict__ WsT,
                                                      const float* __restrict__ bs,
                                                      const float* __restrict__ WdT,
                                                      const float* __restrict__ bd,
                                                      float* __restrict__ out_sparse,
                                                      float* __restrict__ v) {
  __shared__ float accL[4][32];
  __shared__ float sL[4][256];
  __shared__ float red[8][4][32];   // [p][tt][c]
  int b = blockIdx.x >> 5, tq = blockIdx.x & 31;
  int t0 = tq * 4;
  int tid = threadIdx.x;
  if (tid < 128)
    accL[tid >> 5][tid & 31] = acc[b * 4096 + (t0 + (tid >> 5)) * 32 + (tid & 31)];
  __syncthreads();
  float bsv = bs[tid];
  float s0 = bsv, s1 = bsv, s2 = bsv, s3 = bsv;
  for (int m = 0; m < 32; ++m) {
    float w = WsT[m * 256 + tid];
    s0 += w * accL[0][m]; s1 += w * accL[1][m];
    s2 += w * accL[2][m]; s3 += w * accL[3][m];
  }
  s0 = fmaxf(s0, 0.f); s1 = fmaxf(s1, 0.f); s2 = fmaxf(s2, 0.f); s3 = fmaxf(s3, 0.f);
  float* os = out_sparse + b * 32768 + tid * 128 + t0;
  os[0] = s0; os[1] = s1; os[2] = s2; os[3] = s3;
  sL[0][tid] = s0; sL[1][tid] = s1; sL[2][tid] = s2; sL[3][tid] = s3;
  __syncthreads();
  int c = tid & 31, p = tid >> 5;
  float p0 = 0.f, p1 = 0.f, p2 = 0.f, p3 = 0.f;
  for (int jj = 0; jj < 32; ++jj) {
    int o2 = p * 32 + jj;
    float w = WdT[o2 * 32 + c];
    p0 += w * sL[0][o2]; p1 += w * sL[1][o2];
    p2 += w * sL[2][o2]; p3 += w * sL[3][o2];
  }
  red[p][0][c] = p0; red[p][1][c] = p1; red[p][2][c] = p2; red[p][3][c] = p3;
  __syncthreads();
  if (tid < 128) {
    int tt = tid >> 5, cc = tid & 31;
    float vv = bd[cc];
#pragma unroll
    for (int p2i = 0; p2i < 8; ++p2i) vv += red[p2i][tt][cc];
    v[b * 4096 + cc * 128 + t0 + tt] = vv;
  }
}

// ---------------- fused overlap-add + B-pack (res buffer eliminated) ----------------
// res[c][s] = frames[c][g][j0] + (g>0)*frames[c][g-1][j0+1024], s=(8o+j)*256+r,
// g=(8o+j)>>2, j0=((8o+j)&3)*256+r. Packed straight to bf16 hi/lo B fragments.
__global__ __launch_bounds__(256) void k_obpack(const float* __restrict__ frames,
                                                short* __restrict__ Bh,
                                                short* __restrict__ Bl) {
  int c = blockIdx.x >> 4, o = blockIdx.x & 15;
  int r = threadIdx.x;
  bf16x8 hv, lv;
#pragma unroll
  for (int j = 0; j < 8; ++j) {
    int fo = 8 * o + j;
    int g  = fo >> 2;
    int j0 = ((fo & 3) << 8) + r;
    float val = frames[(c * 32 + g) * 2048 + j0];
    if (g > 0) val += frames[(c * 32 + g - 1) * 2048 + j0 + 1024];
    unsigned bits = __float_as_uint(val);
    float rem = val - __uint_as_float(bits & 0xffff0000u);
    hv[j] = (short)(bits >> 16);
    lv[j] = (short)(__float_as_uint(rem) >> 16);
  }
  int unit = (blockIdx.x * 16 + (r >> 4)) * 16 + (r & 15);
  ((bf16x8*)Bh)[unit] = hv;
  ((bf16x8*)Bl)[unit] = lv;
}

// ---------------- final conv as MFMA GEMM, v4: XCD-group swizzle ----------------
// v3 post-mortem: occupancy 1.1->4 waves/SIMD bought only ~20% (44.8 -> ~37 us
// inferred). Static work is ~4-5 us -> ~85% stall on B loads. Bh+Bl = 4 MB =
// exactly one XCD's L2; with default round-robin placement every XCD touches
// ~all of B -> L2 thrash, B served from Infinity Cache (~600-900 cy). v4: all
// 32 batch-blocks of one (j,uc) group (same 512 KB B slice) are pinned to one
// XCD via bijective blockIdx remap exploiting the i%8 XCD round-robin. Per-XCD
// B working set ~1-1.5 MB -> L2-resident. Mapping is perf-only (any dispatch
// change keeps correctness). Compute structure identical to v3 (validated).
__global__ __launch_bounds__(512, 4) void k_conv(const float* __restrict__ v,
                                                 const short* __restrict__ Bh,
                                                 const short* __restrict__ Bl,
                                                 float* __restrict__ y) {
  __shared__ __align__(16) short AH[32 * 264];   // [row 32][K 256 + pad 8]
  __shared__ __align__(16) short AL[32 * 264];
  __shared__ float vwin[2][16][48];              // [c-half][c_local][ii]

  // --- XCD-group swizzle: group e (20 of them) -> XCD e%8; batches fill slots.
  // phys = blockIdx.x; xcd = phys&7, slot = phys>>3 (0..79).
  // slot<32: e=xcd, b=slot; slot<64: e=xcd+8, b=slot-32;
  // else: xcd<4 -> e=xcd+16, b=slot-64 (b 0..15);
  //       xcd>=4 -> e=xcd+12, b=slot-48 (b 16..31).  Bijection over [0,640).
  int xcd  = blockIdx.x & 7;
  int slot = blockIdx.x >> 3;
  int e, b;
  if      (slot < 32) { e = xcd;      b = slot; }
  else if (slot < 64) { e = xcd + 8;  b = slot - 32; }
  else                { e = (xcd < 4) ? (xcd + 16) : (xcd + 12);
                        b = (xcd < 4) ? (slot - 64) : (slot - 48); }
  int j, uc;
  if      (e < 2)  { j = 0; uc = e; }
  else if (e < 6)  { j = 1; uc = e - 2; }
  else if (e < 12) { j = 2; uc = e - 6; }
  else             { j = 3; uc = e - 12; }
  int D0 = 32 * j - 16 * uc;       // d = D0 - 15 + ii, ii in [0,46]

  // stage compact v windows (both c-halves): 2*16*47 floats
  for (int i = threadIdx.x; i < 1504; i += 512) {
    int ii = i % 47;
    int r  = i / 47;               // 0..31
    int c  = r & 15, ph = r >> 4;
    int d  = D0 - 15 + ii;
    vwin[ph][c][ii] = (d >= 0 && d < 128)
        ? v[b * 4096 + (16 * ph + c) * 128 + d] : 0.f;
  }
  __syncthreads();

  int lane = threadIdx.x & 63, wave = threadIdx.x >> 6;
  int quad = lane >> 4, l15 = lane & 15;
  int cq   = quad >> 1;            // low bit of c
  int og   = 2 * uc + (quad & 1);  // global u-octet
  int nt0  = wave * 2;             // 8 waves x 2 nt = 16 nt

  f32x4 acc00 = (f32x4)0.f, acc01 = (f32x4)0.f;   // [qs][t]
  f32x4 acc10 = (f32x4)0.f, acc11 = (f32x4)0.f;

  const bf16x8* AH8 = (const bf16x8*)AH;
  const bf16x8* AL8 = (const bf16x8*)AL;
  const bf16x8* Bh8 = (const bf16x8*)Bh;
  const bf16x8* Bl8 = (const bf16x8*)Bl;
  short2* AH2 = (short2*)AH;
  short2* AL2 = (short2*)AL;

  int abase0 = (0 * 16 + l15) * 33 + quad;   // bf16x8 units, row stride 33
  int abase1 = (1 * 16 + l15) * 33 + quad;

  for (int p = 0; p < 2; ++p) {
    // expand Toeplitz A (hi/lo split) for this c-half: 32 rows x 128 kk-pairs
    for (int i = threadIdx.x; i < 4096; i += 512) {
      int kk2 = i & 127;           // kk = 2*kk2 (pair shares c_local)
      int row = i >> 7;            // 0..31
      int cl  = kk2 >> 3;
      int uu  = (kk2 & 7) * 2;
      int ii  = row - uu + 15;
      float v0 = vwin[p][cl][ii];
      float v1 = vwin[p][cl][ii - 1];
      unsigned w0 = __float_as_uint(v0), w1 = __float_as_uint(v1);
      float r0 = v0 - __uint_as_float(w0 & 0xffff0000u);
      float r1 = v1 - __uint_as_float(w1 & 0xffff0000u);
      int u2 = row * 132 + kk2;    // short2 units, row stride 132
      AH2[u2] = make_short2((short)(w0 >> 16), (short)(w1 >> 16));
      AL2[u2] = make_short2((short)(__float_as_uint(r0) >> 16),
                            (short)(__float_as_uint(r1) >> 16));
    }
    __syncthreads();

#pragma unroll
    for (int ks = 0; ks < 8; ++ks) {
      bf16x8 ah0 = AH8[abase0 + ks * 4];
      bf16x8 al0 = AL8[abase0 + ks * 4];
      bf16x8 ah1 = AH8[abase1 + ks * 4];
      bf16x8 al1 = AL8[abase1 + ks * 4];
      int c   = 16 * p + 2 * ks + cq;
      int bb0 = (c * 16 + og) * 256 + l15;
      bf16x8 bh0 = Bh8[bb0 + nt0 * 16];
      bf16x8 bl0 = Bl8[bb0 + nt0 * 16];
      bf16x8 bh1 = Bh8[bb0 + (nt0 + 1) * 16];
      bf16x8 bl1 = Bl8[bb0 + (nt0 + 1) * 16];
      MFMA16(acc00, ah0, bh0); MFMA16(acc00, ah0, bl0); MFMA16(acc00, al0, bh0);
      MFMA16(acc10, ah1, bh0); MFMA16(acc10, ah1, bl0); MFMA16(acc10, al1, bh0);
      MFMA16(acc01, ah0, bh1); MFMA16(acc01, ah0, bl1); MFMA16(acc01, al0, bh1);
      MFMA16(acc11, ah1, bh1); MFMA16(acc11, ah1, bl1); MFMA16(acc11, al1, bh1);
    }
    __syncthreads();               // A consumed; safe to overwrite in next phase
  }

  {
    float* yb0 = y + b * 32768 + (32 * j + 0 * 16 + quad * 4) * 256 + l15;
    float* yb1 = y + b * 32768 + (32 * j + 1 * 16 + quad * 4) * 256 + l15;
#pragma unroll
    for (int reg = 0; reg < 4; ++reg) {
      atomicAdd(yb0 + reg * 256 + (nt0 + 0) * 16, acc00[reg]);
      atomicAdd(yb0 + reg * 256 + (nt0 + 1) * 16, acc01[reg]);
      atomicAdd(yb1 + reg * 256 + (nt0 + 0) * 16, acc10[reg]);
      atomicAdd(yb1 + reg * 256 + (nt0 + 1) * 16, acc11[reg]);
    }
  }
}

extern "C" void kernel_launch(void* const* d_in, const int* in_sizes, int n_in,
                              void* d_out, int out_size, void* d_ws, size_t ws_size,
                              hipStream_t stream) {
  const float* audio = (const float*)d_in[0];
  const float* Win   = (const float*)d_in[1];
  const float* bin   = (const float*)d_in[2];
  const float* bw    = (const float*)d_in[3];
  const float* bb    = (const float*)d_in[4];
  const float* Ws    = (const float*)d_in[5];
  const float* bs    = (const float*)d_in[6];
  const float* Wd    = (const float*)d_in[7];
  const float* bd    = (const float*)d_in[8];
  const float* reson = (const float*)d_in[9];

  float* out = (float*)d_out;           // [0,1048576) = y ; [1048576,2097152) = sparse
  float* ws  = (float*)d_ws;

  float* spec   = ws + WS_SPEC;
  float* h0     = ws + WS_H0;
  float* accb   = ws + WS_ACC;
  float* vbuf   = ws + WS_V;
  float* WT     = ws + WS_WTIN;
  float* WsT    = ws + WS_WST;
  float* WdT    = ws + WS_WDT;
  float* frames = ws + WS_FRAMES;
  // WS_RES region (dead after fusing overlap-add into k_obpack) -> bf16 B packs
  short* Bh = (short*)(ws + WS_RES);               // 1,048,576 bf16 = 2 MB
  short* Bl = (short*)(ws + WS_RES + 524288u);     // 1,048,576 bf16 = 2 MB
  // chain-weight packs live in WS_V until k_sparse_dense overwrites it (after k_chain)
  short* Whg = (short*)(ws + WS_V);                // 16384 bf16 = 32 KB
  short* Wlg = (short*)(ws + WS_V + 8192u);        // 16384 bf16 = 32 KB

  // zero y region (atomicAdd target); d_out is poisoned before every launch
  hipMemsetAsync(d_out, 0, 1048576u * sizeof(float), stream);

  k_prep<<<128, 256, 0, stream>>>(Win, Ws, Wd, bw, WT, WsT, WdT, Whg, Wlg);
  k_fft<<<2560, 256, 0, stream>>>(audio, reson, spec, frames);
  k_obpack<<<512, 256, 0, stream>>>(frames, Bh, Bl);
  k_proj_in<<<512, 256, 0, stream>>>(spec, WT, bin, h0);
  k_chain<<<32, 1024, 0, stream>>>(h0, Whg, Wlg, bb, accb);
  k_sparse_dense<<<1024, 256, 0, stream>>>(accb, WsT, bs, WdT, bd, out + 1048576, vbuf);
  k_conv<<<640, 512, 0, stream>>>(vbuf, Bh, Bl, out);
}